// Round 5
// baseline (1119.243 us; speedup 1.0000x reference)
//
#include <hip/hip_runtime.h>

#define NCH 256
#define NGRAPH 512
#define HID 16
#define POOLB 64                 // pooler blocks
#define WRITEB 448               // writer blocks
#define GPP (NGRAPH / POOLB)     // graphs per pooler (8), interleaved passes

typedef __attribute__((ext_vector_type(4))) float f32x4;

__device__ __forceinline__ f32x4 ldrow(const float* __restrict__ x, int r, size_t coff) {
    return *reinterpret_cast<const f32x4*>(x + (size_t)r * NCH + coff);
}

__device__ __forceinline__ int lower_bound(const int* __restrict__ batch, int n, int v) {
    int lo = 0, hi = n;
    while (lo < hi) { int mid = (lo + hi) >> 1; if (batch[mid] < v) lo = mid + 1; else hi = mid; }
    return lo;
}

// Producer/consumer fused kernel: blocks [0,POOLB) pool+MLP+publish scales;
// blocks [POOLB, POOLB+WRITEB) stream out = x * scale[batch[r]] as flags land.
// Grid = 512 blocks x 512 thr = exactly 2 blocks/CU -> all resident, no deadlock.
__global__ __launch_bounds__(512, 4) void graph_se_pc(
    const float* __restrict__ x,
    const int* __restrict__ batch,
    const float* __restrict__ W1,
    const float* __restrict__ W2,
    float* __restrict__ out,
    int* __restrict__ flags,
    float* __restrict__ scales,
    int n)
{
    const int tid = threadIdx.x;
    const int rg  = tid >> 6;           // row group 0..7 (wave id)
    const int c4  = tid & 63;           // float4 lane within row
    const size_t coff = (size_t)c4 * 4;

    if (blockIdx.x < POOLB) {
        // ======================= POOLER =======================
        const int p = blockIdx.x;
        __shared__ float s_part[8][NCH];
        __shared__ float s_vec[NCH];
        __shared__ float s_hp[HID][17];
        __shared__ float s_h[HID];

        for (int k = 0; k < GPP; ++k) {
            const int g  = k * POOLB + p;       // pass k handles graphs [k*64, k*64+64)
            const int lo = lower_bound(batch, n, g);      // redundant per-thread (uniform)
            const int hi = lower_bound(batch, n, g + 1);
            const int cnt = hi - lo;

            // pool: 8 row-groups, stride 8 rows, 16 loads in flight
            f32x4 acc = (f32x4)(0.f);
            int r = lo + rg;
            for (; r + 120 < hi; r += 128) {
                f32x4 t[16];
                #pragma unroll
                for (int q = 0; q < 16; ++q) t[q] = ldrow(x, r + 8 * q, coff);
                #pragma unroll
                for (int q = 0; q < 16; ++q) acc += t[q];
            }
            for (; r < hi; r += 8) acc += ldrow(x, r, coff);
            *reinterpret_cast<f32x4*>(&s_part[rg][c4 * 4]) = acc;
            __syncthreads();

            // mean
            if (tid < NCH) {
                float m = 0.f;
                #pragma unroll
                for (int i = 0; i < 8; ++i) m += s_part[i][tid];
                m *= (cnt > 0) ? (1.0f / (float)cnt) : 1.0f;
                s_vec[tid] = m;
            }
            __syncthreads();
            // h = relu(mean @ W1)
            if (tid < NCH) {
                const int j = tid >> 4, sub = tid & 15;
                float hp = 0.f;
                #pragma unroll
                for (int i = 0; i < 16; ++i) { int c = sub * 16 + i; hp += s_vec[c] * W1[c * HID + j]; }
                s_hp[j][sub] = hp;
            }
            __syncthreads();
            if (tid < HID) {
                float h = 0.f;
                #pragma unroll
                for (int i = 0; i < 16; ++i) h += s_hp[tid][i];
                s_h[tid] = fmaxf(h, 0.f);
            }
            __syncthreads();
            // scale = sigmoid(h @ W2) -> publish
            if (tid < NCH) {
                float sc = 0.f;
                #pragma unroll
                for (int j = 0; j < HID; ++j) sc += s_h[j] * W2[j * NCH + tid];
                sc = 1.0f / (1.0f + __expf(-sc));
                scales[(size_t)g * NCH + tid] = sc;
                __threadfence();
            }
            __syncthreads();
            if (tid == 0) {
                __hip_atomic_store(&flags[g], 1, __ATOMIC_RELEASE, __HIP_MEMORY_SCOPE_AGENT);
            }
            __syncthreads();   // safe to reuse s_part next pass
        }
    } else {
        // ======================= WRITER =======================
        const int w = blockIdx.x - POOLB;
        const int chunk = (n + WRITEB - 1) / WRITEB;
        const int r0 = w * chunk;
        const int r1 = min(n, r0 + chunk);

        int rs = r0;
        while (rs < r1) {
            const int g = batch[rs];                 // uniform across block
            // segment end within [rs, r1)
            int lo2 = rs + 1, hi2 = r1;
            while (lo2 < hi2) { int mid = (lo2 + hi2) >> 1; if (batch[mid] <= g) lo2 = mid + 1; else hi2 = mid; }
            const int re = lo2;

            if (tid == 0) {
                while (__hip_atomic_load(&flags[g], __ATOMIC_ACQUIRE, __HIP_MEMORY_SCOPE_AGENT) == 0)
                    __builtin_amdgcn_s_sleep(32);
            }
            __syncthreads();

            const f32x4 scv = *reinterpret_cast<const f32x4*>(scales + (size_t)g * NCH + coff);

            int r = rs + rg;
            for (; r + 24 < re; r += 32) {
                f32x4 v0 = ldrow(x, r     , coff);
                f32x4 v1 = ldrow(x, r +  8, coff);
                f32x4 v2 = ldrow(x, r + 16, coff);
                f32x4 v3 = ldrow(x, r + 24, coff);
                f32x4 o0 = v0 * scv, o1 = v1 * scv, o2 = v2 * scv, o3 = v3 * scv;
                __builtin_nontemporal_store(o0, reinterpret_cast<f32x4*>(out + (size_t)(r     ) * NCH + coff));
                __builtin_nontemporal_store(o1, reinterpret_cast<f32x4*>(out + (size_t)(r +  8) * NCH + coff));
                __builtin_nontemporal_store(o2, reinterpret_cast<f32x4*>(out + (size_t)(r + 16) * NCH + coff));
                __builtin_nontemporal_store(o3, reinterpret_cast<f32x4*>(out + (size_t)(r + 24) * NCH + coff));
            }
            for (; r < re; r += 8) {
                f32x4 v0 = ldrow(x, r, coff);
                f32x4 o0 = v0 * scv;
                __builtin_nontemporal_store(o0, reinterpret_cast<f32x4*>(out + (size_t)r * NCH + coff));
            }
            rs = re;
        }
    }
}

extern "C" void kernel_launch(void* const* d_in, const int* in_sizes, int n_in,
                              void* d_out, int out_size, void* d_ws, size_t ws_size,
                              hipStream_t stream) {
    const float* x     = (const float*)d_in[0];
    const int*   batch = (const int*)d_in[1];
    const float* W1    = (const float*)d_in[2];
    const float* W2    = (const float*)d_in[3];
    float*       out   = (float*)d_out;
    const int n = in_sizes[1];

    int*   flags  = (int*)d_ws;                          // 512 ints
    float* scales = (float*)((char*)d_ws + 4096);        // 512 x 256 floats

    hipMemsetAsync(flags, 0, NGRAPH * sizeof(int), stream);
    hipLaunchKernelGGL(graph_se_pc, dim3(POOLB + WRITEB), dim3(512), 0, stream,
                       x, batch, W1, W2, out, flags, scales, n);
}

// Round 6
// 338.798 us; speedup vs baseline: 3.3036x; 3.3036x over previous
//
#include <hip/hip_runtime.h>

#define NCH 256
#define NGRAPH 512
#define HID 16

typedef __attribute__((ext_vector_type(4))) float f32x4;

__device__ __forceinline__ f32x4 ldrow(const float* __restrict__ x, int r, size_t coff) {
    return *reinterpret_cast<const f32x4*>(x + (size_t)r * NCH + coff);
}

// ---------------- K1: pool + MLP -> scales[512][256] (pure read stream) ----
__global__ __launch_bounds__(512, 4) void pool_mlp_kernel(
    const float* __restrict__ x,
    const int* __restrict__ batch,
    const float* __restrict__ W1,
    const float* __restrict__ W2,
    float* __restrict__ scales,
    int n)
{
    const int g   = blockIdx.x;
    const int tid = threadIdx.x;

    __shared__ int   s_se[2];
    __shared__ float s_part[8][NCH];
    __shared__ float s_vec[NCH];
    __shared__ float s_hp[HID][17];
    __shared__ float s_h[HID];

    if (tid < 2) {
        int v = g + tid;
        int lo = 0, hi = n;
        while (lo < hi) { int mid = (lo + hi) >> 1; if (batch[mid] < v) lo = mid + 1; else hi = mid; }
        s_se[tid] = lo;
    }
    __syncthreads();
    const int start = s_se[0], end = s_se[1];
    const int cnt   = end - start;

    const int rg = tid >> 6;            // row group 0..7
    const int c4 = tid & 63;
    const size_t coff = (size_t)c4 * 4;

    f32x4 acc = (f32x4)(0.f);
    int r = start + rg;
    for (; r + 56 < end; r += 64) {
        f32x4 v0 = ldrow(x, r     , coff);
        f32x4 v1 = ldrow(x, r +  8, coff);
        f32x4 v2 = ldrow(x, r + 16, coff);
        f32x4 v3 = ldrow(x, r + 24, coff);
        f32x4 v4 = ldrow(x, r + 32, coff);
        f32x4 v5 = ldrow(x, r + 40, coff);
        f32x4 v6 = ldrow(x, r + 48, coff);
        f32x4 v7 = ldrow(x, r + 56, coff);
        acc += ((v0 + v1) + (v2 + v3)) + ((v4 + v5) + (v6 + v7));
    }
    for (; r < end; r += 8) acc += ldrow(x, r, coff);
    *reinterpret_cast<f32x4*>(&s_part[rg][c4 * 4]) = acc;
    __syncthreads();

    if (tid < NCH) {
        float m = 0.f;
        #pragma unroll
        for (int i = 0; i < 8; ++i) m += s_part[i][tid];
        m *= (cnt > 0) ? (1.0f / (float)cnt) : 1.0f;
        s_vec[tid] = m;
    }
    __syncthreads();
    if (tid < NCH) {
        const int j = tid >> 4, sub = tid & 15;
        float hp = 0.f;
        #pragma unroll
        for (int i = 0; i < 16; ++i) { int c = sub * 16 + i; hp += s_vec[c] * W1[c * HID + j]; }
        s_hp[j][sub] = hp;
    }
    __syncthreads();
    if (tid < HID) {
        float h = 0.f;
        #pragma unroll
        for (int i = 0; i < 16; ++i) h += s_hp[tid][i];
        s_h[tid] = fmaxf(h, 0.f);
    }
    __syncthreads();
    if (tid < NCH) {
        float sc = 0.f;
        #pragma unroll
        for (int j = 0; j < HID; ++j) sc += s_h[j] * W2[j * NCH + tid];
        scales[(size_t)g * NCH + tid] = 1.0f / (1.0f + __expf(-sc));
    }
}

// ---------------- K2: out = x * scales[batch[row]] (copy-shaped stream) ----
// Flat float4 index space; 64 consecutive float4s = one row, so each wave
// covers exactly one row per unroll slot. Grid-stride, plain stores.
__global__ __launch_bounds__(256, 8) void scale_mul_kernel(
    const float* __restrict__ x,
    const int* __restrict__ batch,
    const float* __restrict__ scales,
    float* __restrict__ out,
    long long n4)                       // n * 64 float4 elements
{
    const long long T = (long long)gridDim.x * blockDim.x;
    long long q0 = (long long)blockIdx.x * blockDim.x + threadIdx.x;

    const f32x4* __restrict__ xv = (const f32x4*)x;
    f32x4* __restrict__ ov       = (f32x4*)out;

    for (; q0 + 3 * T < n4; q0 += 4 * T) {
        long long q1 = q0 + T, q2 = q0 + 2 * T, q3 = q0 + 3 * T;
        f32x4 v0 = xv[q0], v1 = xv[q1], v2 = xv[q2], v3 = xv[q3];
        int g0 = batch[q0 >> 6], g1 = batch[q1 >> 6], g2 = batch[q2 >> 6], g3 = batch[q3 >> 6];
        f32x4 s0 = *reinterpret_cast<const f32x4*>(scales + (size_t)g0 * NCH + ((int)q0 & 63) * 4);
        f32x4 s1 = *reinterpret_cast<const f32x4*>(scales + (size_t)g1 * NCH + ((int)q1 & 63) * 4);
        f32x4 s2 = *reinterpret_cast<const f32x4*>(scales + (size_t)g2 * NCH + ((int)q2 & 63) * 4);
        f32x4 s3 = *reinterpret_cast<const f32x4*>(scales + (size_t)g3 * NCH + ((int)q3 & 63) * 4);
        ov[q0] = v0 * s0;
        ov[q1] = v1 * s1;
        ov[q2] = v2 * s2;
        ov[q3] = v3 * s3;
    }
    for (; q0 < n4; q0 += T) {
        f32x4 v = xv[q0];
        int g = batch[q0 >> 6];
        f32x4 s = *reinterpret_cast<const f32x4*>(scales + (size_t)g * NCH + ((int)q0 & 63) * 4);
        ov[q0] = v * s;
    }
}

extern "C" void kernel_launch(void* const* d_in, const int* in_sizes, int n_in,
                              void* d_out, int out_size, void* d_ws, size_t ws_size,
                              hipStream_t stream) {
    const float* x     = (const float*)d_in[0];
    const int*   batch = (const int*)d_in[1];
    const float* W1    = (const float*)d_in[2];
    const float* W2    = (const float*)d_in[3];
    float*       out   = (float*)d_out;
    const int n = in_sizes[1];

    float* scales = (float*)d_ws;    // 512 x 256 floats = 512 KB

    hipLaunchKernelGGL(pool_mlp_kernel, dim3(NGRAPH), dim3(512), 0, stream,
                       x, batch, W1, W2, scales, n);

    const long long n4 = (long long)n * (NCH / 4);
    hipLaunchKernelGGL(scale_mul_kernel, dim3(2048), dim3(256), 0, stream,
                       x, batch, scales, out, n4);
}

// Round 7
// 280.496 us; speedup vs baseline: 3.9902x; 1.2079x over previous
//
#include <hip/hip_runtime.h>

#define NCH 256
#define HID 16
#define NBLK 256   // each block handles graphs b and b+256

typedef __attribute__((ext_vector_type(4))) float f32x4;

__device__ __forceinline__ f32x4 ldrow(const float* __restrict__ x, int r, size_t coff) {
    return *reinterpret_cast<const f32x4*>(x + (size_t)r * NCH + coff);
}

__device__ __forceinline__ void se_mlp(const float* __restrict__ W1,
                                       const float* __restrict__ W2,
                                       float (&s_part)[16][NCH],
                                       int first, int npart, int cnt,
                                       float* __restrict__ s_vec,
                                       float (&s_hp)[HID][17], float (&s_h)[HID],
                                       int tid)
{
    if (tid < NCH) {
        float m = 0.f;
        for (int i = 0; i < npart; ++i) m += s_part[first + i][tid];
        m *= (cnt > 0) ? (1.0f / (float)cnt) : 1.0f;
        s_vec[tid] = m;
    }
    __syncthreads();
    if (tid < NCH) {
        const int j = tid >> 4, sub = tid & 15;
        float hp = 0.f;
        #pragma unroll
        for (int i = 0; i < 16; ++i) { int c = sub * 16 + i; hp += s_vec[c] * W1[c * HID + j]; }
        s_hp[j][sub] = hp;
    }
    __syncthreads();
    if (tid < HID) {
        float h = 0.f;
        #pragma unroll
        for (int i = 0; i < 16; ++i) h += s_hp[tid][i];
        s_h[tid] = fmaxf(h, 0.f);
    }
    __syncthreads();
    if (tid < NCH) {
        float sc = 0.f;
        #pragma unroll
        for (int j = 0; j < HID; ++j) sc += s_h[j] * W2[j * NCH + tid];
        s_vec[tid] = 1.0f / (1.0f + __expf(-sc));
    }
}

__global__ __launch_bounds__(1024, 8) void graph_se_kernel(
    const float* __restrict__ x,
    const int* __restrict__ batch,
    const float* __restrict__ W1,
    const float* __restrict__ W2,
    float* __restrict__ out,
    int n)
{
    const int b   = blockIdx.x;
    const int tid = threadIdx.x;

    __shared__ int   s_bnd[4];
    __shared__ float s_part[16][NCH];
    __shared__ float s_vecA[NCH];
    __shared__ float s_vecB[NCH];
    __shared__ float s_hp[HID][17];
    __shared__ float s_h[HID];

    // boundaries of graphs b, b+1, b+256, b+257 (batch sorted)
    if (tid < 4) {
        int v = (tid < 2) ? (b + tid) : (NBLK + b + (tid - 2));
        int lo = 0, hi = n;
        while (lo < hi) { int mid = (lo + hi) >> 1; if (batch[mid] < v) lo = mid + 1; else hi = mid; }
        s_bnd[tid] = lo;
    }
    __syncthreads();
    const int loA = s_bnd[0], hiA = s_bnd[1];
    const int loB = s_bnd[2], hiB = s_bnd[3];

    const int rg = tid >> 6;            // row group 0..15 (wave id)
    const int c4 = tid & 63;            // float4 lane within row
    const size_t coff = (size_t)c4 * 4;

    // ---- P1: pool A, 16 groups, 16 loads in flight ----
    {
        f32x4 acc = (f32x4)(0.f);
        int r = loA + rg;
        for (; r + 240 < hiA; r += 256) {
            f32x4 t[16];
            #pragma unroll
            for (int q = 0; q < 16; ++q) t[q] = ldrow(x, r + 16 * q, coff);
            #pragma unroll
            for (int q = 0; q < 16; ++q) acc += t[q];
        }
        for (; r < hiA; r += 16) acc += ldrow(x, r, coff);
        *reinterpret_cast<f32x4*>(&s_part[rg][c4 * 4]) = acc;
    }
    __syncthreads();

    // ---- MLP A -> s_vecA ----
    se_mlp(W1, W2, s_part, 0, 16, hiA - loA, s_vecA, s_hp, s_h, tid);
    __syncthreads();

    // ---- P3: waves 0-7 scale+write A  ||  waves 8-15 pool B ----
    if (rg < 8) {
        const f32x4 scv = *reinterpret_cast<const f32x4*>(&s_vecA[c4 * 4]);
        int r = loA + rg;
        for (; r + 24 < hiA; r += 32) {
            f32x4 v0 = ldrow(x, r     , coff);
            f32x4 v1 = ldrow(x, r +  8, coff);
            f32x4 v2 = ldrow(x, r + 16, coff);
            f32x4 v3 = ldrow(x, r + 24, coff);
            f32x4 o0 = v0 * scv, o1 = v1 * scv, o2 = v2 * scv, o3 = v3 * scv;
            __builtin_nontemporal_store(o0, reinterpret_cast<f32x4*>(out + (size_t)(r     ) * NCH + coff));
            __builtin_nontemporal_store(o1, reinterpret_cast<f32x4*>(out + (size_t)(r +  8) * NCH + coff));
            __builtin_nontemporal_store(o2, reinterpret_cast<f32x4*>(out + (size_t)(r + 16) * NCH + coff));
            __builtin_nontemporal_store(o3, reinterpret_cast<f32x4*>(out + (size_t)(r + 24) * NCH + coff));
        }
        for (; r < hiA; r += 8) {
            f32x4 v0 = ldrow(x, r, coff);
            f32x4 o0 = v0 * scv;
            __builtin_nontemporal_store(o0, reinterpret_cast<f32x4*>(out + (size_t)r * NCH + coff));
        }
    } else {
        const int gid = rg - 8;
        f32x4 acc = (f32x4)(0.f);
        int r = loB + gid;
        for (; r + 56 < hiB; r += 64) {
            f32x4 v0 = ldrow(x, r     , coff);
            f32x4 v1 = ldrow(x, r +  8, coff);
            f32x4 v2 = ldrow(x, r + 16, coff);
            f32x4 v3 = ldrow(x, r + 24, coff);
            f32x4 v4 = ldrow(x, r + 32, coff);
            f32x4 v5 = ldrow(x, r + 40, coff);
            f32x4 v6 = ldrow(x, r + 48, coff);
            f32x4 v7 = ldrow(x, r + 56, coff);
            acc += ((v0 + v1) + (v2 + v3)) + ((v4 + v5) + (v6 + v7));
        }
        for (; r < hiB; r += 8) acc += ldrow(x, r, coff);
        *reinterpret_cast<f32x4*>(&s_part[rg][c4 * 4]) = acc;
    }
    __syncthreads();

    // ---- MLP B (partials 8..15) -> s_vecB ----
    se_mlp(W1, W2, s_part, 8, 8, hiB - loB, s_vecB, s_hp, s_h, tid);
    __syncthreads();

    // ---- P5: scale+write B, 16 groups ----
    {
        const f32x4 scv = *reinterpret_cast<const f32x4*>(&s_vecB[c4 * 4]);
        int r = loB + rg;
        for (; r + 48 < hiB; r += 64) {
            f32x4 v0 = ldrow(x, r     , coff);
            f32x4 v1 = ldrow(x, r + 16, coff);
            f32x4 v2 = ldrow(x, r + 32, coff);
            f32x4 v3 = ldrow(x, r + 48, coff);
            f32x4 o0 = v0 * scv, o1 = v1 * scv, o2 = v2 * scv, o3 = v3 * scv;
            __builtin_nontemporal_store(o0, reinterpret_cast<f32x4*>(out + (size_t)(r     ) * NCH + coff));
            __builtin_nontemporal_store(o1, reinterpret_cast<f32x4*>(out + (size_t)(r + 16) * NCH + coff));
            __builtin_nontemporal_store(o2, reinterpret_cast<f32x4*>(out + (size_t)(r + 32) * NCH + coff));
            __builtin_nontemporal_store(o3, reinterpret_cast<f32x4*>(out + (size_t)(r + 48) * NCH + coff));
        }
        for (; r < hiB; r += 16) {
            f32x4 v0 = ldrow(x, r, coff);
            f32x4 o0 = v0 * scv;
            __builtin_nontemporal_store(o0, reinterpret_cast<f32x4*>(out + (size_t)r * NCH + coff));
        }
    }
}

extern "C" void kernel_launch(void* const* d_in, const int* in_sizes, int n_in,
                              void* d_out, int out_size, void* d_ws, size_t ws_size,
                              hipStream_t stream) {
    const float* x     = (const float*)d_in[0];
    const int*   batch = (const int*)d_in[1];
    const float* W1    = (const float*)d_in[2];
    const float* W2    = (const float*)d_in[3];
    float*       out   = (float*)d_out;
    const int n = in_sizes[1];

    hipLaunchKernelGGL(graph_se_kernel, dim3(NBLK), dim3(1024), 0, stream,
                       x, batch, W1, W2, out, n);
}